// Round 4
// baseline (1183.349 us; speedup 1.0000x reference)
//
#include <hip/hip_runtime.h>
#include <hip/hip_bf16.h>
#include <cstdint>
#include <cstddef>

// Problem constants
#define NB 8192          // batch rows
// NINP=256, NHID=1024, NB_OUT=8, BS_OUT=128, ATT_OUT=512

__device__ __forceinline__ float sigmoidf_(float x) { return 1.0f / (1.0f + expf(-x)); }

// ---------------------------------------------------------------------------
// Generic f32 NN GEMM: C[m,n] = sum_k A[m,k] * W[k,n]
// Block 256 threads, 64x64 tile, 4x4 micro-tile per thread.
// ---------------------------------------------------------------------------
__global__ __launch_bounds__(256) void gemm_nn(
    const float* __restrict__ A, int lda, int aZ,
    const float* __restrict__ W, int wZ, int ldw,
    float* __restrict__ C, int ldc, int cZ,
    int K)
{
    __shared__ float As[16][68];
    __shared__ float Ws[16][64];

    const int tid = threadIdx.x;
    const int tx = tid & 15, ty = tid >> 4;
    const int rowBase = blockIdx.y * 64;
    const int colBase = blockIdx.x * 64;
    A += (size_t)blockIdx.z * aZ;
    W += (size_t)blockIdx.z * wZ;
    C += (size_t)blockIdx.z * cZ;

    float acc[4][4] = {};
    for (int k0 = 0; k0 < K; k0 += 16) {
#pragma unroll
        for (int i = 0; i < 4; ++i) {
            int e = i * 256 + tid;
            int m = e >> 4, kk = e & 15;
            As[kk][m] = A[(size_t)(rowBase + m) * lda + (k0 + kk)];
        }
#pragma unroll
        for (int i = 0; i < 4; ++i) {
            int e = i * 256 + tid;
            int kk = e >> 6, n = e & 63;
            Ws[kk][n] = W[(size_t)(k0 + kk) * ldw + (colBase + n)];
        }
        __syncthreads();
#pragma unroll
        for (int kk = 0; kk < 16; ++kk) {
            const float4 a4 = *(const float4*)&As[kk][ty * 4];
            const float4 b4 = *(const float4*)&Ws[kk][tx * 4];
            const float a[4] = {a4.x, a4.y, a4.z, a4.w};
            const float b[4] = {b4.x, b4.y, b4.z, b4.w};
#pragma unroll
            for (int i = 0; i < 4; ++i)
#pragma unroll
                for (int j = 0; j < 4; ++j)
                    acc[i][j] = fmaf(a[i], b[j], acc[i][j]);
        }
        __syncthreads();
    }
#pragma unroll
    for (int i = 0; i < 4; ++i) {
        float* Cr = C + (size_t)(rowBase + ty * 4 + i) * ldc + colBase + tx * 4;
#pragma unroll
        for (int j = 0; j < 4; ++j) Cr[j] = acc[i][j];
    }
}

// ---------------------------------------------------------------------------
// Same GEMM but with float64 accumulation/output (top-k score path, which
// must match the (likely f64) numpy reference's ordering).
// ---------------------------------------------------------------------------
__global__ __launch_bounds__(256) void gemm_nn_d(
    const float* __restrict__ A, int lda, int aZ,
    const float* __restrict__ W, int wZ, int ldw,
    double* __restrict__ C, int ldc, int cZ,
    int K)
{
    __shared__ float As[16][68];
    __shared__ float Ws[16][64];

    const int tid = threadIdx.x;
    const int tx = tid & 15, ty = tid >> 4;
    const int rowBase = blockIdx.y * 64;
    const int colBase = blockIdx.x * 64;
    A += (size_t)blockIdx.z * aZ;
    W += (size_t)blockIdx.z * wZ;
    C += (size_t)blockIdx.z * cZ;

    double acc[4][4] = {};
    for (int k0 = 0; k0 < K; k0 += 16) {
#pragma unroll
        for (int i = 0; i < 4; ++i) {
            int e = i * 256 + tid;
            int m = e >> 4, kk = e & 15;
            As[kk][m] = A[(size_t)(rowBase + m) * lda + (k0 + kk)];
        }
#pragma unroll
        for (int i = 0; i < 4; ++i) {
            int e = i * 256 + tid;
            int kk = e >> 6, n = e & 63;
            Ws[kk][n] = W[(size_t)(k0 + kk) * ldw + (colBase + n)];
        }
        __syncthreads();
#pragma unroll
        for (int kk = 0; kk < 16; ++kk) {
            const float4 a4 = *(const float4*)&As[kk][ty * 4];
            const float4 b4 = *(const float4*)&Ws[kk][tx * 4];
            const float a[4] = {a4.x, a4.y, a4.z, a4.w};
            const float b[4] = {b4.x, b4.y, b4.z, b4.w};
#pragma unroll
            for (int i = 0; i < 4; ++i)
#pragma unroll
                for (int j = 0; j < 4; ++j)
                    acc[i][j] = fma((double)a[i], (double)b[j], acc[i][j]);
        }
        __syncthreads();
    }
#pragma unroll
    for (int i = 0; i < 4; ++i) {
        double* Cr = C + (size_t)(rowBase + ty * 4 + i) * ldc + colBase + tx * 4;
#pragma unroll
        for (int j = 0; j < 4; ++j) Cr[j] = acc[i][j];
    }
}

// ---------------------------------------------------------------------------
// Per-row (f64): s_k = q[b,k,:]·kk1[b,:]/8 ; c = sigmoid(s);
// mask: 4 smallest s (ties: lower index first) get 0, rest 1.
// ---------------------------------------------------------------------------
__global__ __launch_bounds__(256) void score_mask_k(
    const double* __restrict__ qbuf,   // [B,8,64]
    const double* __restrict__ kk1,    // [B,64]
    float* __restrict__ cbuf,          // [B,8]
    float* __restrict__ maskb)         // [B,8]
{
    const int b = blockIdx.x * 256 + threadIdx.x;   // < 8192
    const double* kr = kk1 + (size_t)b * 64;
    double s[8];
#pragma unroll
    for (int k = 0; k < 8; ++k) {
        const double* qr = qbuf + (size_t)b * 512 + k * 64;
        double acc = 0.0;
#pragma unroll
        for (int d = 0; d < 64; ++d) acc = fma(qr[d], kr[d], acc);
        s[k] = acc / 8.0;
    }
#pragma unroll
    for (int k = 0; k < 8; ++k) {
        int rank = 0;
#pragma unroll
        for (int j = 0; j < 8; ++j)
            rank += (s[j] < s[k]) || (s[j] == s[k] && j < k);
        maskb[(size_t)b * 8 + k] = (rank < 4) ? 0.f : 1.f;
        cbuf[(size_t)b * 8 + k] = (float)(1.0 / (1.0 + exp(-s[k])));
    }
}

// ---------------------------------------------------------------------------
// GRU pointwise for block k. gx = c*gxw + bi ; gh' = ghb + bh.
// ---------------------------------------------------------------------------
__global__ __launch_bounds__(256) void gru_k(
    int k,
    const float* __restrict__ gxw,   // [B,384] = vv1 @ wi[k]
    const float* __restrict__ ghb,   // [B,384] = hq_k @ wh[k]
    const float* __restrict__ cbuf,  // [B,8]
    const float* __restrict__ gbi,   // [8,384]
    const float* __restrict__ gbh,   // [8,384]
    const float* __restrict__ hx,    // [B,1024]
    float* __restrict__ hxn)         // [B,1024]
{
    const int idx = blockIdx.x * 256 + threadIdx.x;  // < 8192*128
    const int j = idx & 127, b = idx >> 7;
    const float cc = cbuf[(size_t)b * 8 + k];
    const float* gx = gxw + (size_t)b * 384;
    const float* gh = ghb + (size_t)b * 384;
    const float* bi = gbi + k * 384;
    const float* bh = gbh + k * 384;
    const float xr = fmaf(cc, gx[j],       bi[j]);
    const float xz = fmaf(cc, gx[128 + j], bi[128 + j]);
    const float xn = fmaf(cc, gx[256 + j], bi[256 + j]);
    const float hr = gh[j]       + bh[j];
    const float hz = gh[128 + j] + bh[128 + j];
    const float hn = gh[256 + j] + bh[256 + j];
    const float r = sigmoidf_(xr + hr);
    const float z = sigmoidf_(xz + hz);
    const float n = tanhf(xn + r * hn);
    const float h = hx[(size_t)b * 1024 + k * 128 + j];
    hxn[(size_t)b * 1024 + k * 128 + j] = (1.f - z) * n + z * h;
}

// ---------------------------------------------------------------------------
// Second attention: 4 heads of 8x8 over dim 16. One thread per (b,h,qb).
// ---------------------------------------------------------------------------
__global__ __launch_bounds__(256) void attn2_k(
    const float* __restrict__ q2, const float* __restrict__ k2,
    const float* __restrict__ v2, float* __restrict__ o)
{
    const int idx = blockIdx.x * 256 + threadIdx.x;  // < 8192*32
    const int qb = idx & 7, h = (idx >> 3) & 3, b = idx >> 5;
    const float* qr = q2 + (size_t)b * 512 + qb * 64 + h * 16;
    float qv[16];
#pragma unroll
    for (int d = 0; d < 16; ++d) qv[d] = qr[d];
    float sc[8];
    float mx = -1e30f;
#pragma unroll
    for (int kb = 0; kb < 8; ++kb) {
        const float* krow = k2 + (size_t)b * 512 + kb * 64 + h * 16;
        float acc = 0.f;
#pragma unroll
        for (int d = 0; d < 16; ++d) acc = fmaf(qv[d], krow[d], acc);
        sc[kb] = acc * 0.25f;
        mx = fmaxf(mx, sc[kb]);
    }
    float sum = 0.f;
#pragma unroll
    for (int kb = 0; kb < 8; ++kb) { sc[kb] = expf(sc[kb] - mx); sum += sc[kb]; }
    const float inv = 1.f / sum;
#pragma unroll
    for (int dd = 0; dd < 16; ++dd) {
        float acc = 0.f;
#pragma unroll
        for (int kb = 0; kb < 8; ++kb)
            acc = fmaf(sc[kb], v2[(size_t)b * 512 + kb * 64 + h * 16 + dd], acc);
        o[(size_t)b * 512 + qb * 64 + h * 16 + dd] = acc * inv;
    }
}

// ---------------------------------------------------------------------------
// Final: att = sigmoid(o@gate_w+gate_b)*tanh(o@fc_w+fc_b); masked combine.
// FLOAT32 outputs: out[0:B*1024] = hx_out, out[B*1024:2*B*1024] = mask_full.
// ---------------------------------------------------------------------------
__global__ __launch_bounds__(256) void final_k(
    const float* __restrict__ o, const float* __restrict__ hxn,
    const float* __restrict__ hx, const float* __restrict__ maskb,
    const float* __restrict__ fc_w, const float* __restrict__ fc_b,
    const float* __restrict__ gate_w, const float* __restrict__ gate_b,
    float* __restrict__ out)
{
    const int idx = blockIdx.x * 256 + threadIdx.x;   // < 8192*1024
    const int j = idx & 127, qb = (idx >> 7) & 7, b = idx >> 10;
    const float* orow = o + (size_t)b * 512 + qb * 64;
    float ag = 0.f, af = 0.f;
#pragma unroll
    for (int d = 0; d < 64; ++d) {
        const float ov = orow[d];
        ag = fmaf(ov, gate_w[d * 128 + j], ag);
        af = fmaf(ov, fc_w[d * 128 + j], af);
    }
    const float att = sigmoidf_(ag + gate_b[j]) * tanhf(af + fc_b[j]);
    const float hnv = hxn[idx] + att;
    const float m = maskb[(size_t)b * 8 + qb];
    const float hold = hx[idx];
    out[idx] = m * hnv + (1.f - m) * hold;
    out[(size_t)NB * 1024 + idx] = m;
}

// ---------------------------------------------------------------------------
extern "C" void kernel_launch(void* const* d_in, const int* in_sizes, int n_in,
                              void* d_out, int out_size, void* d_ws, size_t ws_size,
                              hipStream_t stream)
{
    (void)in_sizes; (void)n_in; (void)out_size; (void)ws_size;
    const float* inp    = (const float*)d_in[0];
    const float* hx     = (const float*)d_in[1];
    // d_in[2] = step (unused)
    const float* Wq1    = (const float*)d_in[3];
    const float* Wk1    = (const float*)d_in[4];
    const float* Wv1    = (const float*)d_in[5];
    const float* Wq2    = (const float*)d_in[6];
    const float* Wk2    = (const float*)d_in[7];
    const float* Wv2    = (const float*)d_in[8];
    const float* fc_w   = (const float*)d_in[9];
    const float* fc_b   = (const float*)d_in[10];
    const float* gate_w = (const float*)d_in[11];
    const float* gate_b = (const float*)d_in[12];
    const float* gwi    = (const float*)d_in[13];
    const float* gwh    = (const float*)d_in[14];
    const float* gbi    = (const float*)d_in[15];
    const float* gbh    = (const float*)d_in[16];
    float* out = (float*)d_out;

    // workspace layout; total ~125 MB
    double* kk1d  = (double*)d_ws;                       // [B,64]  f64  (4 MB)
    double* qbufd = kk1d + (size_t)NB * 64;              // [B,512] f64  (32 MB)
    float*  fbase = (float*)(qbufd + (size_t)NB * 512);
    size_t off = 0;
    float* vv1   = fbase + off; off += (size_t)NB * 512;   // 16 MB; later k2
    float* cbuf  = fbase + off; off += (size_t)NB * 8;
    float* maskb = fbase + off; off += (size_t)NB * 8;
    float* gxw   = fbase + off; off += (size_t)NB * 384;   // per-k
    float* ghb   = fbase + off; off += (size_t)NB * 384;   // per-k
    float* hxn   = fbase + off; off += (size_t)NB * 1024;  // 32 MB
    float* q2    = fbase + off; off += (size_t)NB * 512;   // 16 MB
    float* k2   = vv1;              // alias: vv1 dead after last gxw GEMM
    float* v2   = gxw;              // alias: gxw/ghb dead after GRU loop (24MB >= 16MB)
    float* obuf = (float*)qbufd;    // alias: qbufd dead after score_mask

    const dim3 blk(256);

    // f64 score path: kk1 = inp @ Wk1[1]; q = hq @ Wq1 (batched k)
    gemm_nn_d<<<dim3(1, 128, 1), blk, 0, stream>>>(inp, 256, 0, Wk1 + 256 * 64, 0, 64, kk1d, 64, 0, 256);
    gemm_nn_d<<<dim3(1, 128, 8), blk, 0, stream>>>(hx, 1024, 128, Wq1, 128 * 64, 64, qbufd, 512, 64, 128);
    // vv1 = inp @ Wv1[1]  (f32)
    gemm_nn<<<dim3(8, 128, 1), blk, 0, stream>>>(inp, 256, 0, Wv1 + 256 * 512, 0, 512, vv1, 512, 0, 256);
    // scores (f64), sigmoid coeff c, top-k mask
    score_mask_k<<<dim3(32), blk, 0, stream>>>(qbufd, kk1d, cbuf, maskb);

    // GRU per block k
    for (int k = 0; k < 8; ++k) {
        gemm_nn<<<dim3(6, 128, 1), blk, 0, stream>>>(vv1, 512, 0, gwi + (size_t)k * 512 * 384, 0, 384, gxw, 384, 0, 512);
        gemm_nn<<<dim3(6, 128, 1), blk, 0, stream>>>(hx + k * 128, 1024, 0, gwh + (size_t)k * 128 * 384, 0, 384, ghb, 384, 0, 128);
        gru_k<<<dim3(4096), blk, 0, stream>>>(k, gxw, ghb, cbuf, gbi, gbh, hx, hxn);
    }

    // q2/k2/v2 = hxn_k @ W*2 (batched k)
    gemm_nn<<<dim3(1, 128, 8), blk, 0, stream>>>(hxn, 1024, 128, Wq2, 128 * 64, 64, q2, 512, 64, 128);
    gemm_nn<<<dim3(1, 128, 8), blk, 0, stream>>>(hxn, 1024, 128, Wk2, 128 * 64, 64, k2, 512, 64, 128);
    gemm_nn<<<dim3(1, 128, 8), blk, 0, stream>>>(hxn, 1024, 128, Wv2, 128 * 64, 64, v2, 512, 64, 128);

    // attention-2 -> o
    attn2_k<<<dim3(1024), blk, 0, stream>>>(q2, k2, v2, obuf);
    // gate/fc + residual + mask combine -> f32 outputs
    final_k<<<dim3(32768), blk, 0, stream>>>(obuf, hxn, hx, maskb, fc_w, fc_b, gate_w, gate_b, out);
}

// Round 5
// 402.597 us; speedup vs baseline: 2.9393x; 2.9393x over previous
//
#include <hip/hip_runtime.h>
#include <cstdint>
#include <cstddef>

#define NB 8192
// NINP=256, NHID=1024, NB_OUT=8, BS_OUT=128, ATT_OUT=512

typedef __attribute__((ext_vector_type(4))) float f32x4;
typedef __attribute__((ext_vector_type(8))) short bf16x8;

__device__ __forceinline__ float sigmoidf_(float x){ return 1.0f/(1.0f+expf(-x)); }

__device__ __forceinline__ unsigned short f2bf(float f){
    union { float f; unsigned u; } v; v.f = f;
    unsigned u = v.u;
    return (unsigned short)((u + 0x7fffu + ((u >> 16) & 1u)) >> 16);
}
__device__ __forceinline__ float bf2f(unsigned short b){
    union { unsigned u; float f; } v; v.u = ((unsigned)b) << 16;
    return v.f;
}
__device__ __forceinline__ void ld8f(const unsigned short* p, float* f){
    uint4 u = *(const uint4*)p;
    f[0]=bf2f(u.x&0xffff); f[1]=bf2f(u.x>>16);
    f[2]=bf2f(u.y&0xffff); f[3]=bf2f(u.y>>16);
    f[4]=bf2f(u.z&0xffff); f[5]=bf2f(u.z>>16);
    f[6]=bf2f(u.w&0xffff); f[7]=bf2f(u.w>>16);
}

// ---------------------------------------------------------------------------
// f64-accum GEMM (score path only). A,W f32; C f32. 64x64 tile, VALU.
// ---------------------------------------------------------------------------
__global__ __launch_bounds__(256) void gemm_nn_d(
    const float* __restrict__ A, int lda, int aZ,
    const float* __restrict__ W, int wZ, int ldw,
    float* __restrict__ C, int ldc, int cZ,
    int K)
{
    __shared__ float As[16][68];
    __shared__ float Ws[16][64];
    const int tid = threadIdx.x;
    const int tx = tid & 15, ty = tid >> 4;
    const int rowBase = blockIdx.y * 64;
    const int colBase = blockIdx.x * 64;
    A += (size_t)blockIdx.z * aZ;
    W += (size_t)blockIdx.z * wZ;
    C += (size_t)blockIdx.z * cZ;

    double acc[4][4] = {};
    for (int k0 = 0; k0 < K; k0 += 16) {
#pragma unroll
        for (int i = 0; i < 4; ++i) {
            int e = i * 256 + tid;
            int m = e >> 4, kk = e & 15;
            As[kk][m] = A[(size_t)(rowBase + m) * lda + (k0 + kk)];
        }
#pragma unroll
        for (int i = 0; i < 4; ++i) {
            int e = i * 256 + tid;
            int kk = e >> 6, n = e & 63;
            Ws[kk][n] = W[(size_t)(k0 + kk) * ldw + (colBase + n)];
        }
        __syncthreads();
#pragma unroll
        for (int kk = 0; kk < 16; ++kk) {
            const float4 a4 = *(const float4*)&As[kk][ty * 4];
            const float4 b4 = *(const float4*)&Ws[kk][tx * 4];
            const float a[4] = {a4.x, a4.y, a4.z, a4.w};
            const float b[4] = {b4.x, b4.y, b4.z, b4.w};
#pragma unroll
            for (int i = 0; i < 4; ++i)
#pragma unroll
                for (int j = 0; j < 4; ++j)
                    acc[i][j] = fma((double)a[i], (double)b[j], acc[i][j]);
        }
        __syncthreads();
    }
#pragma unroll
    for (int i = 0; i < 4; ++i) {
        float* Cr = C + (size_t)(rowBase + ty * 4 + i) * ldc + colBase + tx * 4;
#pragma unroll
        for (int j = 0; j < 4; ++j) Cr[j] = (float)acc[i][j];
    }
}

// ---------------------------------------------------------------------------
// Score + mask: s_k = q·kk1/8 (f64 dot of f32 inputs); c=sigmoid(s);
// 4 smallest s (ties: lower idx) -> mask 0.
// ---------------------------------------------------------------------------
__global__ __launch_bounds__(256) void score_mask_k(
    const float* __restrict__ qbuf,   // [B,8,64]
    const float* __restrict__ kk1,    // [B,64]
    float* __restrict__ cbuf,         // [B,8]
    float* __restrict__ maskb)        // [B,8]
{
    const int b = blockIdx.x * 256 + threadIdx.x;
    const float* kr = kk1 + (size_t)b * 64;
    double s[8];
#pragma unroll
    for (int k = 0; k < 8; ++k) {
        const float* qr = qbuf + (size_t)b * 512 + k * 64;
        double acc = 0.0;
#pragma unroll
        for (int d = 0; d < 64; ++d) acc = fma((double)qr[d], (double)kr[d], acc);
        s[k] = acc / 8.0;
    }
#pragma unroll
    for (int k = 0; k < 8; ++k) {
        int rank = 0;
#pragma unroll
        for (int j = 0; j < 8; ++j)
            rank += (s[j] < s[k]) || (s[j] == s[k] && j < k);
        maskb[(size_t)b * 8 + k] = (rank < 4) ? 0.f : 1.f;
        cbuf[(size_t)b * 8 + k] = (float)(1.0 / (1.0 + exp(-s[k])));
    }
}

// ---------------------------------------------------------------------------
// Weight prep: transpose/convert weights to bf16 [N][K] layouts.
// ---------------------------------------------------------------------------
__global__ __launch_bounds__(256) void prep_w(
    const float* __restrict__ gwi, const float* __restrict__ gwh,
    const float* __restrict__ Wq2, const float* __restrict__ Wk2, const float* __restrict__ Wv2,
    const float* __restrict__ gate_w, const float* __restrict__ fc_w,
    unsigned short* __restrict__ wi_t,   // [8][384][512]
    unsigned short* __restrict__ wh_t,   // [8][384][128]
    unsigned short* __restrict__ w2_t,   // [8][192][128]
    unsigned short* __restrict__ gfc_t)  // [2][128][64]
{
    int idx = blockIdx.x * 256 + threadIdx.x;
    const int N1 = 8*384*512, N2 = 8*384*128, N3 = 8*192*128, N4 = 2*128*64;
    if (idx < N1) {
        int k = idx / 196608, r = idx % 196608, j = r / 512, e = r % 512;
        wi_t[idx] = f2bf(gwi[((size_t)k*512 + e)*384 + j]); return;
    }
    idx -= N1;
    if (idx < N2) {
        int k = idx / 49152, r = idx % 49152, j = r / 128, d = r % 128;
        wh_t[idx] = f2bf(gwh[((size_t)k*128 + d)*384 + j]); return;
    }
    idx -= N2;
    if (idx < N3) {
        int k = idx / 24576, r = idx % 24576, n = r / 128, d = r % 128;
        const float* Wsrc = (n < 64) ? Wq2 : ((n < 128) ? Wk2 : Wv2);
        w2_t[idx] = f2bf(Wsrc[((size_t)k*128 + d)*64 + (n & 63)]); return;
    }
    idx -= N3;
    if (idx < N4) {
        int g = idx / 8192, r = idx % 8192, j = r / 64, d = r % 64;
        gfc_t[idx] = f2bf((g ? fc_w : gate_w)[d*128 + j]);
    }
}

// ---------------------------------------------------------------------------
// Generic bf16 MFMA GEMM. 64x64 tile, 4 waves (2x2), 16x16x32 frags.
// A row-major [M][K] (f32 or bf16 src); Bt = B^T bf16 [N][K] (row stride ldb=K).
// EPI 0: C bf16, C[row*ldc + z*cZ + col]. EPI 1: transposed C[z*cZ + col*ldc + row].
// ---------------------------------------------------------------------------
template<int ASRC_F32, int EPI>
__global__ __launch_bounds__(256) void gemm_bf(
    const void* __restrict__ Av, int lda, int aZ,
    const unsigned short* __restrict__ Bt, int bZ, int ldb,
    unsigned short* __restrict__ C, int ldc, long cZ,
    int K)
{
    __shared__ unsigned short As[64][72];
    __shared__ unsigned short Bs[64][72];
    const int tid = threadIdx.x;
    const int wave = tid >> 6, lane = tid & 63;
    const int wr = wave >> 1, wc = wave & 1;
    const int lr = lane & 15, lo = lane >> 4;
    const int rowBase = blockIdx.y * 64, colBase = blockIdx.x * 64;
    const int z = blockIdx.z;

    const f32x4 zero = {0.f, 0.f, 0.f, 0.f};
    f32x4 acc[2][2];
    acc[0][0]=zero; acc[0][1]=zero; acc[1][0]=zero; acc[1][1]=zero;

    const unsigned short* B = Bt + (size_t)z * bZ;
    for (int k0 = 0; k0 < K; k0 += 64) {
        if (ASRC_F32) {
            const float* A = (const float*)Av + (size_t)z * aZ;
#pragma unroll
            for (int i = 0; i < 4; ++i) {
                int c = i*256 + tid;
                int r = c >> 4, kc = (c & 15) << 2;
                float4 a4 = *(const float4*)(A + (size_t)(rowBase + r) * lda + k0 + kc);
                unsigned short* p = &As[r][kc];
                p[0]=f2bf(a4.x); p[1]=f2bf(a4.y); p[2]=f2bf(a4.z); p[3]=f2bf(a4.w);
            }
        } else {
            const unsigned short* A = (const unsigned short*)Av + (size_t)z * aZ;
#pragma unroll
            for (int i = 0; i < 2; ++i) {
                int c = i*256 + tid;
                int r = c >> 3, kc = (c & 7) << 3;
                *(uint4*)&As[r][kc] = *(const uint4*)(A + (size_t)(rowBase + r) * lda + k0 + kc);
            }
        }
#pragma unroll
        for (int i = 0; i < 2; ++i) {
            int c = i*256 + tid;
            int n = c >> 3, kc = (c & 7) << 3;
            *(uint4*)&Bs[n][kc] = *(const uint4*)(B + (size_t)(colBase + n) * ldb + k0 + kc);
        }
        __syncthreads();
#pragma unroll
        for (int ks = 0; ks < 64; ks += 32) {
            bf16x8 a0 = *(const bf16x8*)&As[wr*32 + lr][ks + lo*8];
            bf16x8 a1 = *(const bf16x8*)&As[wr*32 + 16 + lr][ks + lo*8];
            bf16x8 b0 = *(const bf16x8*)&Bs[wc*32 + lr][ks + lo*8];
            bf16x8 b1 = *(const bf16x8*)&Bs[wc*32 + 16 + lr][ks + lo*8];
            acc[0][0] = __builtin_amdgcn_mfma_f32_16x16x32_bf16(a0,b0,acc[0][0],0,0,0);
            acc[0][1] = __builtin_amdgcn_mfma_f32_16x16x32_bf16(a0,b1,acc[0][1],0,0,0);
            acc[1][0] = __builtin_amdgcn_mfma_f32_16x16x32_bf16(a1,b0,acc[1][0],0,0,0);
            acc[1][1] = __builtin_amdgcn_mfma_f32_16x16x32_bf16(a1,b1,acc[1][1],0,0,0);
        }
        __syncthreads();
    }
#pragma unroll
    for (int i = 0; i < 2; ++i)
#pragma unroll
    for (int j = 0; j < 2; ++j)
#pragma unroll
    for (int r = 0; r < 4; ++r) {
        int row = rowBase + wr*32 + i*16 + lo*4 + r;
        int col = colBase + wc*32 + j*16 + lr;
        float v = acc[i][j][r];
        if (EPI == 0) C[(size_t)row * ldc + (size_t)z * cZ + col] = f2bf(v);
        else          C[(size_t)z * cZ + (size_t)col * ldc + row] = f2bf(v);
    }
}

// ---------------------------------------------------------------------------
// Fused GRU-input GEMM: acc1 = inp @ wc_t[z] (K=256), acc2 = hx_z @ wh_t[z] (K=128).
// Epilogue: v1 = c*acc1+gbi, v2 = acc2+gbh; comb[z][row][512]:
//   col<256: v1+v2 ; col>=256: xn at col, hn at col+128.
// ---------------------------------------------------------------------------
__global__ __launch_bounds__(256) void gemm_gxh(
    const float* __restrict__ inp,            // [8192][256]
    const unsigned short* __restrict__ wc_t,  // [8][384][256]
    const float* __restrict__ hx,             // [8192][1024]
    const unsigned short* __restrict__ wh_t,  // [8][384][128]
    const float* __restrict__ cbuf,           // [8192][8]
    const float* __restrict__ gbi, const float* __restrict__ gbh,  // [8][384]
    unsigned short* __restrict__ comb)        // [8][8192][512]
{
    __shared__ unsigned short As[64][72];
    __shared__ unsigned short Bs[64][72];
    const int tid = threadIdx.x;
    const int wave = tid >> 6, lane = tid & 63;
    const int wr = wave >> 1, wc = wave & 1;
    const int lr = lane & 15, lo = lane >> 4;
    const int rowBase = blockIdx.y * 64, colBase = blockIdx.x * 64;
    const int z = blockIdx.z;

    const f32x4 zero = {0.f, 0.f, 0.f, 0.f};
    f32x4 acc1[2][2], acc2[2][2];
    acc1[0][0]=zero; acc1[0][1]=zero; acc1[1][0]=zero; acc1[1][1]=zero;
    acc2[0][0]=zero; acc2[0][1]=zero; acc2[1][0]=zero; acc2[1][1]=zero;

    // phase 1: inp @ wc_t  (K=256)
    const unsigned short* B1 = wc_t + (size_t)z * (384*256);
    for (int k0 = 0; k0 < 256; k0 += 64) {
#pragma unroll
        for (int i = 0; i < 4; ++i) {
            int c = i*256 + tid;
            int r = c >> 4, kc = (c & 15) << 2;
            float4 a4 = *(const float4*)(inp + (size_t)(rowBase + r) * 256 + k0 + kc);
            unsigned short* p = &As[r][kc];
            p[0]=f2bf(a4.x); p[1]=f2bf(a4.y); p[2]=f2bf(a4.z); p[3]=f2bf(a4.w);
        }
#pragma unroll
        for (int i = 0; i < 2; ++i) {
            int c = i*256 + tid;
            int n = c >> 3, kc = (c & 7) << 3;
            *(uint4*)&Bs[n][kc] = *(const uint4*)(B1 + (size_t)(colBase + n) * 256 + k0 + kc);
        }
        __syncthreads();
#pragma unroll
        for (int ks = 0; ks < 64; ks += 32) {
            bf16x8 a0 = *(const bf16x8*)&As[wr*32 + lr][ks + lo*8];
            bf16x8 a1 = *(const bf16x8*)&As[wr*32 + 16 + lr][ks + lo*8];
            bf16x8 b0 = *(const bf16x8*)&Bs[wc*32 + lr][ks + lo*8];
            bf16x8 b1 = *(const bf16x8*)&Bs[wc*32 + 16 + lr][ks + lo*8];
            acc1[0][0] = __builtin_amdgcn_mfma_f32_16x16x32_bf16(a0,b0,acc1[0][0],0,0,0);
            acc1[0][1] = __builtin_amdgcn_mfma_f32_16x16x32_bf16(a0,b1,acc1[0][1],0,0,0);
            acc1[1][0] = __builtin_amdgcn_mfma_f32_16x16x32_bf16(a1,b0,acc1[1][0],0,0,0);
            acc1[1][1] = __builtin_amdgcn_mfma_f32_16x16x32_bf16(a1,b1,acc1[1][1],0,0,0);
        }
        __syncthreads();
    }
    // phase 2: hx_z @ wh_t  (K=128)
    const unsigned short* B2 = wh_t + (size_t)z * (384*128);
    for (int k0 = 0; k0 < 128; k0 += 64) {
#pragma unroll
        for (int i = 0; i < 4; ++i) {
            int c = i*256 + tid;
            int r = c >> 4, kc = (c & 15) << 2;
            float4 a4 = *(const float4*)(hx + (size_t)(rowBase + r) * 1024 + z*128 + k0 + kc);
            unsigned short* p = &As[r][kc];
            p[0]=f2bf(a4.x); p[1]=f2bf(a4.y); p[2]=f2bf(a4.z); p[3]=f2bf(a4.w);
        }
#pragma unroll
        for (int i = 0; i < 2; ++i) {
            int c = i*256 + tid;
            int n = c >> 3, kc = (c & 7) << 3;
            *(uint4*)&Bs[n][kc] = *(const uint4*)(B2 + (size_t)(colBase + n) * 128 + k0 + kc);
        }
        __syncthreads();
#pragma unroll
        for (int ks = 0; ks < 64; ks += 32) {
            bf16x8 a0 = *(const bf16x8*)&As[wr*32 + lr][ks + lo*8];
            bf16x8 a1 = *(const bf16x8*)&As[wr*32 + 16 + lr][ks + lo*8];
            bf16x8 b0 = *(const bf16x8*)&Bs[wc*32 + lr][ks + lo*8];
            bf16x8 b1 = *(const bf16x8*)&Bs[wc*32 + 16 + lr][ks + lo*8];
            acc2[0][0] = __builtin_amdgcn_mfma_f32_16x16x32_bf16(a0,b0,acc2[0][0],0,0,0);
            acc2[0][1] = __builtin_amdgcn_mfma_f32_16x16x32_bf16(a0,b1,acc2[0][1],0,0,0);
            acc2[1][0] = __builtin_amdgcn_mfma_f32_16x16x32_bf16(a1,b0,acc2[1][0],0,0,0);
            acc2[1][1] = __builtin_amdgcn_mfma_f32_16x16x32_bf16(a1,b1,acc2[1][1],0,0,0);
        }
        __syncthreads();
    }
    // epilogue
#pragma unroll
    for (int i = 0; i < 2; ++i)
#pragma unroll
    for (int j = 0; j < 2; ++j)
#pragma unroll
    for (int r = 0; r < 4; ++r) {
        int row = rowBase + wr*32 + i*16 + lo*4 + r;
        int col = colBase + wc*32 + j*16 + lr;
        float c = cbuf[(size_t)row * 8 + z];
        float v1 = fmaf(c, acc1[i][j][r], gbi[z*384 + col]);
        float v2 = acc2[i][j][r] + gbh[z*384 + col];
        size_t base = ((size_t)z * 8192 + row) * 512;
        if (col < 256) comb[base + col] = f2bf(v1 + v2);
        else { comb[base + col] = f2bf(v1); comb[base + col + 128] = f2bf(v2); }
    }
}

// ---------------------------------------------------------------------------
// GRU pointwise over all k. comb: [xr+hr | xz+hz | xn | hn].
// ---------------------------------------------------------------------------
__global__ __launch_bounds__(256) void gru_all(
    const unsigned short* __restrict__ comb, const float* __restrict__ hx,
    unsigned short* __restrict__ hxn)
{
    const int idx = blockIdx.x * 256 + threadIdx.x;  // < 8192*1024
    const int j = idx & 127, k = (idx >> 7) & 7, b = idx >> 10;
    const size_t base = ((size_t)k * 8192 + b) * 512;
    const float rz = bf2f(comb[base + j]);
    const float zz = bf2f(comb[base + 128 + j]);
    const float xn = bf2f(comb[base + 256 + j]);
    const float hn = bf2f(comb[base + 384 + j]);
    const float r = sigmoidf_(rz), z = sigmoidf_(zz);
    const float n = tanhf(fmaf(r, hn, xn));
    const float h = hx[idx];
    hxn[idx] = f2bf((1.f - z) * n + z * h);
}

// ---------------------------------------------------------------------------
// Second attention on bf16 qkv [8192][8][192] (q|k|v per block), o bf16 [65536][64].
// ---------------------------------------------------------------------------
__global__ __launch_bounds__(256) void attn2_bf(
    const unsigned short* __restrict__ qkv, unsigned short* __restrict__ o)
{
    const int idx = blockIdx.x * 256 + threadIdx.x;  // < 8192*32
    const int qb = idx & 7, h = (idx >> 3) & 3, b = idx >> 5;
    const unsigned short* rowb = qkv + (size_t)b * 1536;
    float qv[16];
    ld8f(rowb + qb*192 + h*16, qv); ld8f(rowb + qb*192 + h*16 + 8, qv + 8);
    float sc[8]; float mx = -1e30f;
#pragma unroll
    for (int kb = 0; kb < 8; ++kb) {
        float kv[16];
        ld8f(rowb + kb*192 + 64 + h*16, kv); ld8f(rowb + kb*192 + 64 + h*16 + 8, kv + 8);
        float a = 0.f;
#pragma unroll
        for (int d = 0; d < 16; ++d) a = fmaf(qv[d], kv[d], a);
        sc[kb] = a * 0.25f;
        mx = fmaxf(mx, sc[kb]);
    }
    float sum = 0.f;
#pragma unroll
    for (int kb = 0; kb < 8; ++kb) { sc[kb] = expf(sc[kb] - mx); sum += sc[kb]; }
    const float inv = 1.f / sum;
    float oa[16];
#pragma unroll
    for (int d = 0; d < 16; ++d) oa[d] = 0.f;
#pragma unroll
    for (int kb = 0; kb < 8; ++kb) {
        float vv[16];
        ld8f(rowb + kb*192 + 128 + h*16, vv); ld8f(rowb + kb*192 + 128 + h*16 + 8, vv + 8);
#pragma unroll
        for (int d = 0; d < 16; ++d) oa[d] = fmaf(sc[kb], vv[d], oa[d]);
    }
    unsigned short t[16];
#pragma unroll
    for (int d = 0; d < 16; ++d) t[d] = f2bf(oa[d] * inv);
    uint4 u0, u1;
    u0.x = (unsigned)t[0] | ((unsigned)t[1]<<16);  u0.y = (unsigned)t[2] | ((unsigned)t[3]<<16);
    u0.z = (unsigned)t[4] | ((unsigned)t[5]<<16);  u0.w = (unsigned)t[6] | ((unsigned)t[7]<<16);
    u1.x = (unsigned)t[8] | ((unsigned)t[9]<<16);  u1.y = (unsigned)t[10]| ((unsigned)t[11]<<16);
    u1.z = (unsigned)t[12]| ((unsigned)t[13]<<16); u1.w = (unsigned)t[14]| ((unsigned)t[15]<<16);
    unsigned short* op = o + (size_t)(b*8 + qb) * 64 + h*16;
    *(uint4*)op = u0; *(uint4*)(op + 8) = u1;
}

// ---------------------------------------------------------------------------
// Fused gate/fc MFMA + epilogue + mask combine. A = o_bf [65536][64], K=64.
// Bg/Bf from gfc_t [2][128][64]. Outputs f32 hx_out and mask_full.
// ---------------------------------------------------------------------------
__global__ __launch_bounds__(256) void gatefc_final(
    const unsigned short* __restrict__ o,      // [65536][64]
    const unsigned short* __restrict__ gfc_t,  // [2][128][64]
    const float* __restrict__ gate_b, const float* __restrict__ fc_b,
    const unsigned short* __restrict__ hxn,    // [8192][1024] bf16
    const float* __restrict__ hx,              // [8192][1024] f32
    const float* __restrict__ maskb,           // [8192][8]
    float* __restrict__ out)
{
    __shared__ unsigned short As[64][72];
    __shared__ unsigned short Bg[64][72];
    __shared__ unsigned short Bf[64][72];
    const int tid = threadIdx.x;
    const int wave = tid >> 6, lane = tid & 63;
    const int wr = wave >> 1, wc = wave & 1;
    const int lr = lane & 15, lo = lane >> 4;
    const int rowBase = blockIdx.y * 64, colBase = blockIdx.x * 64;

#pragma unroll
    for (int i = 0; i < 2; ++i) {
        int c = i*256 + tid;
        int r = c >> 3, kc = (c & 7) << 3;
        *(uint4*)&As[r][kc] = *(const uint4*)(o + (size_t)(rowBase + r) * 64 + kc);
        *(uint4*)&Bg[r][kc] = *(const uint4*)(gfc_t + (size_t)(colBase + r) * 64 + kc);
        *(uint4*)&Bf[r][kc] = *(const uint4*)(gfc_t + 8192 + (size_t)(colBase + r) * 64 + kc);
    }
    __syncthreads();

    const f32x4 zero = {0.f, 0.f, 0.f, 0.f};
    f32x4 ag[2][2], af[2][2];
    ag[0][0]=zero; ag[0][1]=zero; ag[1][0]=zero; ag[1][1]=zero;
    af[0][0]=zero; af[0][1]=zero; af[1][0]=zero; af[1][1]=zero;
#pragma unroll
    for (int ks = 0; ks < 64; ks += 32) {
        bf16x8 a0 = *(const bf16x8*)&As[wr*32 + lr][ks + lo*8];
        bf16x8 a1 = *(const bf16x8*)&As[wr*32 + 16 + lr][ks + lo*8];
        bf16x8 g0 = *(const bf16x8*)&Bg[wc*32 + lr][ks + lo*8];
        bf16x8 g1 = *(const bf16x8*)&Bg[wc*32 + 16 + lr][ks + lo*8];
        bf16x8 f0 = *(const bf16x8*)&Bf[wc*32 + lr][ks + lo*8];
        bf16x8 f1 = *(const bf16x8*)&Bf[wc*32 + 16 + lr][ks + lo*8];
        ag[0][0] = __builtin_amdgcn_mfma_f32_16x16x32_bf16(a0,g0,ag[0][0],0,0,0);
        ag[0][1] = __builtin_amdgcn_mfma_f32_16x16x32_bf16(a0,g1,ag[0][1],0,0,0);
        ag[1][0] = __builtin_amdgcn_mfma_f32_16x16x32_bf16(a1,g0,ag[1][0],0,0,0);
        ag[1][1] = __builtin_amdgcn_mfma_f32_16x16x32_bf16(a1,g1,ag[1][1],0,0,0);
        af[0][0] = __builtin_amdgcn_mfma_f32_16x16x32_bf16(a0,f0,af[0][0],0,0,0);
        af[0][1] = __builtin_amdgcn_mfma_f32_16x16x32_bf16(a0,f1,af[0][1],0,0,0);
        af[1][0] = __builtin_amdgcn_mfma_f32_16x16x32_bf16(a1,f0,af[1][0],0,0,0);
        af[1][1] = __builtin_amdgcn_mfma_f32_16x16x32_bf16(a1,f1,af[1][1],0,0,0);
    }
#pragma unroll
    for (int i = 0; i < 2; ++i)
#pragma unroll
    for (int j = 0; j < 2; ++j)
#pragma unroll
    for (int r = 0; r < 4; ++r) {
        int m   = rowBase + wr*32 + i*16 + lo*4 + r;
        int col = colBase + wc*32 + j*16 + lr;
        float g = sigmoidf_(ag[i][j][r] + gate_b[col]);
        float f = tanhf(af[i][j][r] + fc_b[col]);
        float att = g * f;
        size_t oidx = (size_t)m * 128 + col;
        float msk = maskb[m];
        float hnv = bf2f(hxn[oidx]) + att;
        out[oidx] = msk * hnv + (1.f - msk) * hx[oidx];
        out[(size_t)NB * 1024 + oidx] = msk;
    }
}

// ---------------------------------------------------------------------------
extern "C" void kernel_launch(void* const* d_in, const int* in_sizes, int n_in,
                              void* d_out, int out_size, void* d_ws, size_t ws_size,
                              hipStream_t stream)
{
    (void)in_sizes; (void)n_in; (void)out_size; (void)ws_size;
    const float* inp    = (const float*)d_in[0];
    const float* hx     = (const float*)d_in[1];
    const float* Wq1    = (const float*)d_in[3];
    const float* Wk1    = (const float*)d_in[4];
    const float* Wv1    = (const float*)d_in[5];
    const float* Wq2    = (const float*)d_in[6];
    const float* Wk2    = (const float*)d_in[7];
    const float* Wv2    = (const float*)d_in[8];
    const float* fc_w   = (const float*)d_in[9];
    const float* fc_b   = (const float*)d_in[10];
    const float* gate_w = (const float*)d_in[11];
    const float* gate_b = (const float*)d_in[12];
    const float* gwi    = (const float*)d_in[13];
    const float* gwh    = (const float*)d_in[14];
    const float* gbi    = (const float*)d_in[15];
    const float* gbh    = (const float*)d_in[16];
    float* out = (float*)d_out;

    // ---- workspace arena (byte offsets; peak ~103 MB) ----
    char* W = (char*)d_ws;
    float* cbuf  = (float*)(W);                     // [8192*8]    256 KB
    float* maskb = (float*)(W + 262144);            // [8192*8]    256 KB
    // score phase (dead after score_mask):
    float* kk1f  = (float*)(W + 524288);            // [8192*64]   2 MB
    float* qbuff = (float*)(W + 524288 + 2097152);  // [8192*512] 16 MB
    // weights (written after score phase, reuse same region):
    unsigned short* wi_t  = (unsigned short*)(W + 524288);            // [8][384][512] 3 MB
    unsigned short* wh_t  = (unsigned short*)(W + 524288 + 3145728);  // [8][384][128] .75 MB
    unsigned short* w2_t  = (unsigned short*)(W + 524288 + 3932160);  // [8][192][128] .375 MB
    unsigned short* gfc_t = (unsigned short*)(W + 524288 + 4325376);  // [2][128][64]  32 KB
    unsigned short* wc_t  = (unsigned short*)(W + 524288 + 4358144);  // [8][384][256] 1.5 MB
    // big buffers:
    unsigned short* comb  = (unsigned short*)(W + 19398656);          // [8][8192][512] 64 MB
    unsigned short* qkv   = (unsigned short*)(W + 19398656);          // reuse comb after gru: 24 MB
    unsigned short* o_bf  = (unsigned short*)(W + 19398656 + 25165824); // 8 MB (within comb area)
    unsigned short* hxn   = (unsigned short*)(W + 86507520);          // [8192][1024] 16 MB

    const dim3 blk(256);

    // (1) score path: f64-accum GEMMs -> f32, then mask
    gemm_nn_d<<<dim3(1, 128, 1), blk, 0, stream>>>(inp, 256, 0, Wk1 + 256*64, 0, 64, kk1f, 64, 0, 256);
    gemm_nn_d<<<dim3(1, 128, 8), blk, 0, stream>>>(hx, 1024, 128, Wq1, 128*64, 64, qbuff, 512, 64, 128);
    score_mask_k<<<dim3(32), blk, 0, stream>>>(qbuff, kk1f, cbuf, maskb);

    // (2) weight prep (transpose+bf16)
    prep_w<<<dim3(8512), blk, 0, stream>>>(gwi, gwh, Wq2, Wk2, Wv2, gate_w, fc_w,
                                           wi_t, wh_t, w2_t, gfc_t);

    // (3) wcomb = Wv1[1] @ gwi  -> transposed bf16 [8][384][256]
    gemm_bf<1, 1><<<dim3(6, 4, 8), blk, 0, stream>>>(
        Wv1 + 256*512, 512, 0, wi_t, 384*512, 512, wc_t, 256, (long)384*256, 512);

    // (4) fused gx/gh GEMM -> comb
    gemm_gxh<<<dim3(6, 128, 8), blk, 0, stream>>>(inp, wc_t, hx, wh_t, cbuf, gbi, gbh, comb);

    // (5) GRU pointwise -> hxn (bf16)
    gru_all<<<dim3(32768), blk, 0, stream>>>(comb, hx, hxn);

    // (6) q2|k2|v2 = hxn_k @ W2cat -> qkv bf16 [8192][1536]
    gemm_bf<0, 0><<<dim3(3, 128, 8), blk, 0, stream>>>(
        hxn, 1024, 128, w2_t, 192*128, 128, qkv, 1536, 192L, 128);

    // (7) attention-2 -> o_bf
    attn2_bf<<<dim3(1024), blk, 0, stream>>>(qkv, o_bf);

    // (8) gate/fc MFMA + mask combine -> f32 outputs
    gatefc_final<<<dim3(2, 1024), blk, 0, stream>>>(o_bf, gfc_t, gate_b, fc_b,
                                                    hxn, hx, maskb, out);
}

// Round 6
// 372.826 us; speedup vs baseline: 3.1740x; 1.0799x over previous
//
#include <hip/hip_runtime.h>
#include <cstdint>
#include <cstddef>

#define NB 8192
// NINP=256, NHID=1024, NB_OUT=8, BS_OUT=128, ATT_OUT=512

typedef __attribute__((ext_vector_type(4))) float f32x4;
typedef __attribute__((ext_vector_type(8))) short bf16x8;

__device__ __forceinline__ float sigmoidf_(float x){ return 1.0f/(1.0f+expf(-x)); }

__device__ __forceinline__ unsigned short f2bf(float f){
    union { float f; unsigned u; } v; v.f = f;
    unsigned u = v.u;
    return (unsigned short)((u + 0x7fffu + ((u >> 16) & 1u)) >> 16);
}
__device__ __forceinline__ float bf2f(unsigned short b){
    union { unsigned u; float f; } v; v.u = ((unsigned)b) << 16;
    return v.f;
}
__device__ __forceinline__ void ld8f(const unsigned short* p, float* f){
    uint4 u = *(const uint4*)p;
    f[0]=bf2f(u.x&0xffff); f[1]=bf2f(u.x>>16);
    f[2]=bf2f(u.y&0xffff); f[3]=bf2f(u.y>>16);
    f[4]=bf2f(u.z&0xffff); f[5]=bf2f(u.z>>16);
    f[6]=bf2f(u.w&0xffff); f[7]=bf2f(u.w>>16);
}

// ---------------------------------------------------------------------------
// f32 VALU GEMM (score path). C = A @ W. 64x64 tile.
// ---------------------------------------------------------------------------
__global__ __launch_bounds__(256) void gemm_nn(
    const float* __restrict__ A, int lda, int aZ,
    const float* __restrict__ W, int wZ, int ldw,
    float* __restrict__ C, int ldc, int cZ,
    int K)
{
    __shared__ float As[16][68];
    __shared__ float Ws[16][64];
    const int tid = threadIdx.x;
    const int tx = tid & 15, ty = tid >> 4;
    const int rowBase = blockIdx.y * 64;
    const int colBase = blockIdx.x * 64;
    A += (size_t)blockIdx.z * aZ;
    W += (size_t)blockIdx.z * wZ;
    C += (size_t)blockIdx.z * cZ;

    float acc[4][4] = {};
    for (int k0 = 0; k0 < K; k0 += 16) {
#pragma unroll
        for (int i = 0; i < 4; ++i) {
            int e = i * 256 + tid;
            int m = e >> 4, kk = e & 15;
            As[kk][m] = A[(size_t)(rowBase + m) * lda + (k0 + kk)];
        }
#pragma unroll
        for (int i = 0; i < 4; ++i) {
            int e = i * 256 + tid;
            int kk = e >> 6, n = e & 63;
            Ws[kk][n] = W[(size_t)(k0 + kk) * ldw + (colBase + n)];
        }
        __syncthreads();
#pragma unroll
        for (int kk = 0; kk < 16; ++kk) {
            const float4 a4 = *(const float4*)&As[kk][ty * 4];
            const float4 b4 = *(const float4*)&Ws[kk][tx * 4];
            const float a[4] = {a4.x, a4.y, a4.z, a4.w};
            const float b[4] = {b4.x, b4.y, b4.z, b4.w};
#pragma unroll
            for (int i = 0; i < 4; ++i)
#pragma unroll
                for (int j = 0; j < 4; ++j)
                    acc[i][j] = fmaf(a[i], b[j], acc[i][j]);
        }
        __syncthreads();
    }
#pragma unroll
    for (int i = 0; i < 4; ++i) {
        float* Cr = C + (size_t)(rowBase + ty * 4 + i) * ldc + colBase + tx * 4;
#pragma unroll
        for (int j = 0; j < 4; ++j) Cr[j] = acc[i][j];
    }
}

// ---------------------------------------------------------------------------
// Score + mask: s_k = q·kk1/8 (f64 dot of f32 GEMM outputs); c=sigmoid(s);
// 4 smallest s (ties: lower idx) -> mask 0.
// ---------------------------------------------------------------------------
__global__ __launch_bounds__(256) void score_mask_k(
    const float* __restrict__ qbuf,   // [B,8,64]
    const float* __restrict__ kk1,    // [B,64]
    float* __restrict__ cbuf,         // [B,8]
    float* __restrict__ maskb)        // [B,8]
{
    const int b = blockIdx.x * 256 + threadIdx.x;
    const float* kr = kk1 + (size_t)b * 64;
    double s[8];
#pragma unroll
    for (int k = 0; k < 8; ++k) {
        const float* qr = qbuf + (size_t)b * 512 + k * 64;
        double acc = 0.0;
#pragma unroll
        for (int d = 0; d < 64; ++d) acc = fma((double)qr[d], (double)kr[d], acc);
        s[k] = acc / 8.0;
    }
#pragma unroll
    for (int k = 0; k < 8; ++k) {
        int rank = 0;
#pragma unroll
        for (int j = 0; j < 8; ++j)
            rank += (s[j] < s[k]) || (s[j] == s[k] && j < k);
        maskb[(size_t)b * 8 + k] = (rank < 4) ? 0.f : 1.f;
        cbuf[(size_t)b * 8 + k] = (float)(1.0 / (1.0 + exp(-s[k])));
    }
}

// ---------------------------------------------------------------------------
// Cast inp (2M f32) and hx (8M f32) to bf16 (vectorized, 4/thread).
// ---------------------------------------------------------------------------
__global__ __launch_bounds__(256) void cast_bf(
    const float* __restrict__ inp, const float* __restrict__ hx,
    unsigned short* __restrict__ inp_bf, unsigned short* __restrict__ hx_bf)
{
    const int idx = blockIdx.x * 256 + threadIdx.x;   // < 2621440
    const int NI = 524288;  // 2M f32 / 4
    const float* src; unsigned short* dst; int i;
    if (idx < NI) { src = inp; dst = inp_bf; i = idx; }
    else          { src = hx;  dst = hx_bf;  i = idx - NI; }
    float4 v = *(const float4*)(src + (size_t)i * 4);
    uint2 u;
    u.x = (unsigned)f2bf(v.x) | ((unsigned)f2bf(v.y) << 16);
    u.y = (unsigned)f2bf(v.z) | ((unsigned)f2bf(v.w) << 16);
    *(uint2*)(dst + (size_t)i * 4) = u;
}

// ---------------------------------------------------------------------------
// Weight prep: transpose/convert weights to bf16 [N][K] layouts.
// ---------------------------------------------------------------------------
__global__ __launch_bounds__(256) void prep_w(
    const float* __restrict__ gwi, const float* __restrict__ gwh,
    const float* __restrict__ Wq2, const float* __restrict__ Wk2, const float* __restrict__ Wv2,
    const float* __restrict__ gate_w, const float* __restrict__ fc_w,
    unsigned short* __restrict__ wi_t,   // [8][384][512]
    unsigned short* __restrict__ wh_t,   // [8][384][128]
    unsigned short* __restrict__ w2_t,   // [8][192][128]
    unsigned short* __restrict__ gfc_t)  // [2][128][64]
{
    int idx = blockIdx.x * 256 + threadIdx.x;
    const int N1 = 8*384*512, N2 = 8*384*128, N3 = 8*192*128, N4 = 2*128*64;
    if (idx < N1) {
        int k = idx / 196608, r = idx % 196608, j = r / 512, e = r % 512;
        wi_t[idx] = f2bf(gwi[((size_t)k*512 + e)*384 + j]); return;
    }
    idx -= N1;
    if (idx < N2) {
        int k = idx / 49152, r = idx % 49152, j = r / 128, d = r % 128;
        wh_t[idx] = f2bf(gwh[((size_t)k*128 + d)*384 + j]); return;
    }
    idx -= N2;
    if (idx < N3) {
        int k = idx / 24576, r = idx % 24576, n = r / 128, d = r % 128;
        const float* Wsrc = (n < 64) ? Wq2 : ((n < 128) ? Wk2 : Wv2);
        w2_t[idx] = f2bf(Wsrc[((size_t)k*128 + d)*64 + (n & 63)]); return;
    }
    idx -= N3;
    if (idx < N4) {
        int g = idx / 8192, r = idx % 8192, j = r / 64, d = r % 64;
        gfc_t[idx] = f2bf((g ? fc_w : gate_w)[d*128 + j]);
    }
}

// ---------------------------------------------------------------------------
// Generic bf16 MFMA GEMM. 64x64 tile, 4 waves (2x2), 16x16x32 frags.
// A row-major [M][K] (f32 or bf16 src); Bt = B^T bf16 [N][K].
// EPI 0: C bf16 C[row*ldc + z*cZ + col]. EPI 1: transposed C[z*cZ + col*ldc + row].
// ---------------------------------------------------------------------------
template<int ASRC_F32, int EPI>
__global__ __launch_bounds__(256) void gemm_bf(
    const void* __restrict__ Av, int lda, int aZ,
    const unsigned short* __restrict__ Bt, int bZ, int ldb,
    unsigned short* __restrict__ C, int ldc, long cZ,
    int K)
{
    __shared__ unsigned short As[64][72];
    __shared__ unsigned short Bs[64][72];
    const int tid = threadIdx.x;
    const int wave = tid >> 6, lane = tid & 63;
    const int wr = wave >> 1, wc = wave & 1;
    const int lr = lane & 15, lo = lane >> 4;
    const int rowBase = blockIdx.y * 64, colBase = blockIdx.x * 64;
    const int z = blockIdx.z;

    const f32x4 zero = {0.f, 0.f, 0.f, 0.f};
    f32x4 acc[2][2];
    acc[0][0]=zero; acc[0][1]=zero; acc[1][0]=zero; acc[1][1]=zero;

    const unsigned short* B = Bt + (size_t)z * bZ;
    for (int k0 = 0; k0 < K; k0 += 64) {
        if (ASRC_F32) {
            const float* A = (const float*)Av + (size_t)z * aZ;
#pragma unroll
            for (int i = 0; i < 4; ++i) {
                int c = i*256 + tid;
                int r = c >> 4, kc = (c & 15) << 2;
                float4 a4 = *(const float4*)(A + (size_t)(rowBase + r) * lda + k0 + kc);
                unsigned short* p = &As[r][kc];
                p[0]=f2bf(a4.x); p[1]=f2bf(a4.y); p[2]=f2bf(a4.z); p[3]=f2bf(a4.w);
            }
        } else {
            const unsigned short* A = (const unsigned short*)Av + (size_t)z * aZ;
#pragma unroll
            for (int i = 0; i < 2; ++i) {
                int c = i*256 + tid;
                int r = c >> 3, kc = (c & 7) << 3;
                *(uint4*)&As[r][kc] = *(const uint4*)(A + (size_t)(rowBase + r) * lda + k0 + kc);
            }
        }
#pragma unroll
        for (int i = 0; i < 2; ++i) {
            int c = i*256 + tid;
            int n = c >> 3, kc = (c & 7) << 3;
            *(uint4*)&Bs[n][kc] = *(const uint4*)(B + (size_t)(colBase + n) * ldb + k0 + kc);
        }
        __syncthreads();
#pragma unroll
        for (int ks = 0; ks < 64; ks += 32) {
            bf16x8 a0 = *(const bf16x8*)&As[wr*32 + lr][ks + lo*8];
            bf16x8 a1 = *(const bf16x8*)&As[wr*32 + 16 + lr][ks + lo*8];
            bf16x8 b0 = *(const bf16x8*)&Bs[wc*32 + lr][ks + lo*8];
            bf16x8 b1 = *(const bf16x8*)&Bs[wc*32 + 16 + lr][ks + lo*8];
            acc[0][0] = __builtin_amdgcn_mfma_f32_16x16x32_bf16(a0,b0,acc[0][0],0,0,0);
            acc[0][1] = __builtin_amdgcn_mfma_f32_16x16x32_bf16(a0,b1,acc[0][1],0,0,0);
            acc[1][0] = __builtin_amdgcn_mfma_f32_16x16x32_bf16(a1,b0,acc[1][0],0,0,0);
            acc[1][1] = __builtin_amdgcn_mfma_f32_16x16x32_bf16(a1,b1,acc[1][1],0,0,0);
        }
        __syncthreads();
    }
#pragma unroll
    for (int i = 0; i < 2; ++i)
#pragma unroll
    for (int j = 0; j < 2; ++j)
#pragma unroll
    for (int r = 0; r < 4; ++r) {
        int row = rowBase + wr*32 + i*16 + lo*4 + r;
        int col = colBase + wc*32 + j*16 + lr;
        float v = acc[i][j][r];
        if (EPI == 0) C[(size_t)row * ldc + (size_t)z * cZ + col] = f2bf(v);
        else          C[(size_t)z * cZ + (size_t)col * ldc + row] = f2bf(v);
    }
}

// ---------------------------------------------------------------------------
// Fused GRU-input GEMM, N=128 per block (NTILE=2), bf16 A inputs.
// acc1 = inp_bf @ wc_t[z] (K=256), acc2 = hx_bf_z @ wh_t[z] (K=128).
// Epilogue -> comb[z][row][512]: [xr+hr | xz+hz | xn | hn].
// ---------------------------------------------------------------------------
__global__ __launch_bounds__(256) void gemm_gxh(
    const unsigned short* __restrict__ inp_bf,  // [8192][256]
    const unsigned short* __restrict__ wc_t,    // [8][384][256]
    const unsigned short* __restrict__ hx_bf,   // [8192][1024]
    const unsigned short* __restrict__ wh_t,    // [8][384][128]
    const float* __restrict__ cbuf,             // [8192][8]
    const float* __restrict__ gbi, const float* __restrict__ gbh,  // [8][384]
    unsigned short* __restrict__ comb)          // [8][8192][512]
{
    __shared__ unsigned short As[64][72];
    __shared__ unsigned short Bs[128][72];
    const int tid = threadIdx.x;
    const int wave = tid >> 6, lane = tid & 63;
    const int wr = wave >> 1, wc = wave & 1;
    const int lr = lane & 15, lo = lane >> 4;
    const int rowBase = blockIdx.y * 64, colBase = blockIdx.x * 128;
    const int z = blockIdx.z;

    const f32x4 zero = {0.f, 0.f, 0.f, 0.f};
    f32x4 acc1[2][2][2], acc2[2][2][2];
#pragma unroll
    for (int t = 0; t < 2; ++t)
#pragma unroll
    for (int i = 0; i < 2; ++i)
#pragma unroll
    for (int j = 0; j < 2; ++j) { acc1[t][i][j] = zero; acc2[t][i][j] = zero; }

    // phase 1: inp_bf @ wc_t[z]  (K=256)
    const unsigned short* B1 = wc_t + (size_t)z * (384*256);
    for (int k0 = 0; k0 < 256; k0 += 64) {
#pragma unroll
        for (int i = 0; i < 2; ++i) {
            int c = i*256 + tid;
            int r = c >> 3, kc = (c & 7) << 3;
            *(uint4*)&As[r][kc] = *(const uint4*)(inp_bf + (size_t)(rowBase + r) * 256 + k0 + kc);
        }
#pragma unroll
        for (int i = 0; i < 4; ++i) {
            int c = i*256 + tid;
            int n = c >> 3, kc = (c & 7) << 3;
            *(uint4*)&Bs[n][kc] = *(const uint4*)(B1 + (size_t)(colBase + n) * 256 + k0 + kc);
        }
        __syncthreads();
#pragma unroll
        for (int ks = 0; ks < 64; ks += 32) {
            bf16x8 a0 = *(const bf16x8*)&As[wr*32 + lr][ks + lo*8];
            bf16x8 a1 = *(const bf16x8*)&As[wr*32 + 16 + lr][ks + lo*8];
#pragma unroll
            for (int t = 0; t < 2; ++t) {
                bf16x8 b0 = *(const bf16x8*)&Bs[t*64 + wc*32 + lr][ks + lo*8];
                bf16x8 b1 = *(const bf16x8*)&Bs[t*64 + wc*32 + 16 + lr][ks + lo*8];
                acc1[t][0][0] = __builtin_amdgcn_mfma_f32_16x16x32_bf16(a0,b0,acc1[t][0][0],0,0,0);
                acc1[t][0][1] = __builtin_amdgcn_mfma_f32_16x16x32_bf16(a0,b1,acc1[t][0][1],0,0,0);
                acc1[t][1][0] = __builtin_amdgcn_mfma_f32_16x16x32_bf16(a1,b0,acc1[t][1][0],0,0,0);
                acc1[t][1][1] = __builtin_amdgcn_mfma_f32_16x16x32_bf16(a1,b1,acc1[t][1][1],0,0,0);
            }
        }
        __syncthreads();
    }
    // phase 2: hx_bf_z @ wh_t[z]  (K=128)
    const unsigned short* B2 = wh_t + (size_t)z * (384*128);
    for (int k0 = 0; k0 < 128; k0 += 64) {
#pragma unroll
        for (int i = 0; i < 2; ++i) {
            int c = i*256 + tid;
            int r = c >> 3, kc = (c & 7) << 3;
            *(uint4*)&As[r][kc] = *(const uint4*)(hx_bf + (size_t)(rowBase + r) * 1024 + z*128 + k0 + kc);
        }
#pragma unroll
        for (int i = 0; i < 4; ++i) {
            int c = i*256 + tid;
            int n = c >> 3, kc = (c & 7) << 3;
            *(uint4*)&Bs[n][kc] = *(const uint4*)(B2 + (size_t)(colBase + n) * 128 + k0 + kc);
        }
        __syncthreads();
#pragma unroll
        for (int ks = 0; ks < 64; ks += 32) {
            bf16x8 a0 = *(const bf16x8*)&As[wr*32 + lr][ks + lo*8];
            bf16x8 a1 = *(const bf16x8*)&As[wr*32 + 16 + lr][ks + lo*8];
#pragma unroll
            for (int t = 0; t < 2; ++t) {
                bf16x8 b0 = *(const bf16x8*)&Bs[t*64 + wc*32 + lr][ks + lo*8];
                bf16x8 b1 = *(const bf16x8*)&Bs[t*64 + wc*32 + 16 + lr][ks + lo*8];
                acc2[t][0][0] = __builtin_amdgcn_mfma_f32_16x16x32_bf16(a0,b0,acc2[t][0][0],0,0,0);
                acc2[t][0][1] = __builtin_amdgcn_mfma_f32_16x16x32_bf16(a0,b1,acc2[t][0][1],0,0,0);
                acc2[t][1][0] = __builtin_amdgcn_mfma_f32_16x16x32_bf16(a1,b0,acc2[t][1][0],0,0,0);
                acc2[t][1][1] = __builtin_amdgcn_mfma_f32_16x16x32_bf16(a1,b1,acc2[t][1][1],0,0,0);
            }
        }
        __syncthreads();
    }
    // epilogue
#pragma unroll
    for (int t = 0; t < 2; ++t)
#pragma unroll
    for (int i = 0; i < 2; ++i)
#pragma unroll
    for (int j = 0; j < 2; ++j)
#pragma unroll
    for (int r = 0; r < 4; ++r) {
        int row = rowBase + wr*32 + i*16 + lo*4 + r;
        int col = colBase + t*64 + wc*32 + j*16 + lr;
        float c = cbuf[(size_t)row * 8 + z];
        float v1 = fmaf(c, acc1[t][i][j][r], gbi[z*384 + col]);
        float v2 = acc2[t][i][j][r] + gbh[z*384 + col];
        size_t base = ((size_t)z * 8192 + row) * 512;
        if (col < 256) comb[base + col] = f2bf(v1 + v2);
        else { comb[base + col] = f2bf(v1); comb[base + col + 128] = f2bf(v2); }
    }
}

// ---------------------------------------------------------------------------
// GRU pointwise over all k. comb: [xr+hr | xz+hz | xn | hn].
// ---------------------------------------------------------------------------
__global__ __launch_bounds__(256) void gru_all(
    const unsigned short* __restrict__ comb, const float* __restrict__ hx,
    unsigned short* __restrict__ hxn)
{
    const int idx = blockIdx.x * 256 + threadIdx.x;  // < 8192*1024
    const int j = idx & 127, k = (idx >> 7) & 7, b = idx >> 10;
    const size_t base = ((size_t)k * 8192 + b) * 512;
    const float rz = bf2f(comb[base + j]);
    const float zz = bf2f(comb[base + 128 + j]);
    const float xn = bf2f(comb[base + 256 + j]);
    const float hn = bf2f(comb[base + 384 + j]);
    const float r = sigmoidf_(rz), z = sigmoidf_(zz);
    const float n = tanhf(fmaf(r, hn, xn));
    const float h = hx[idx];
    hxn[idx] = f2bf((1.f - z) * n + z * h);
}

// ---------------------------------------------------------------------------
// Second attention on bf16 qkv [8192][8][192], o bf16 [65536][64].
// ---------------------------------------------------------------------------
__global__ __launch_bounds__(256) void attn2_bf(
    const unsigned short* __restrict__ qkv, unsigned short* __restrict__ o)
{
    const int idx = blockIdx.x * 256 + threadIdx.x;  // < 8192*32
    const int qb = idx & 7, h = (idx >> 3) & 3, b = idx >> 5;
    const unsigned short* rowb = qkv + (size_t)b * 1536;
    float qv[16];
    ld8f(rowb + qb*192 + h*16, qv); ld8f(rowb + qb*192 + h*16 + 8, qv + 8);
    float sc[8]; float mx = -1e30f;
#pragma unroll
    for (int kb = 0; kb < 8; ++kb) {
        float kv[16];
        ld8f(rowb + kb*192 + 64 + h*16, kv); ld8f(rowb + kb*192 + 64 + h*16 + 8, kv + 8);
        float a = 0.f;
#pragma unroll
        for (int d = 0; d < 16; ++d) a = fmaf(qv[d], kv[d], a);
        sc[kb] = a * 0.25f;
        mx = fmaxf(mx, sc[kb]);
    }
    float sum = 0.f;
#pragma unroll
    for (int kb = 0; kb < 8; ++kb) { sc[kb] = expf(sc[kb] - mx); sum += sc[kb]; }
    const float inv = 1.f / sum;
    float oa[16];
#pragma unroll
    for (int d = 0; d < 16; ++d) oa[d] = 0.f;
#pragma unroll
    for (int kb = 0; kb < 8; ++kb) {
        float vv[16];
        ld8f(rowb + kb*192 + 128 + h*16, vv); ld8f(rowb + kb*192 + 128 + h*16 + 8, vv + 8);
#pragma unroll
        for (int d = 0; d < 16; ++d) oa[d] = fmaf(sc[kb], vv[d], oa[d]);
    }
    unsigned short t[16];
#pragma unroll
    for (int d = 0; d < 16; ++d) t[d] = f2bf(oa[d] * inv);
    uint4 u0, u1;
    u0.x = (unsigned)t[0] | ((unsigned)t[1]<<16);  u0.y = (unsigned)t[2] | ((unsigned)t[3]<<16);
    u0.z = (unsigned)t[4] | ((unsigned)t[5]<<16);  u0.w = (unsigned)t[6] | ((unsigned)t[7]<<16);
    u1.x = (unsigned)t[8] | ((unsigned)t[9]<<16);  u1.y = (unsigned)t[10]| ((unsigned)t[11]<<16);
    u1.z = (unsigned)t[12]| ((unsigned)t[13]<<16); u1.w = (unsigned)t[14]| ((unsigned)t[15]<<16);
    unsigned short* op = o + (size_t)(b*8 + qb) * 64 + h*16;
    *(uint4*)op = u0; *(uint4*)(op + 8) = u1;
}

// ---------------------------------------------------------------------------
// Fused gate/fc MFMA + epilogue + mask combine -> f32 outputs.
// ---------------------------------------------------------------------------
__global__ __launch_bounds__(256) void gatefc_final(
    const unsigned short* __restrict__ o,      // [65536][64]
    const unsigned short* __restrict__ gfc_t,  // [2][128][64]
    const float* __restrict__ gate_b, const float* __restrict__ fc_b,
    const unsigned short* __restrict__ hxn,    // [8192][1024] bf16
    const float* __restrict__ hx,              // [8192][1024] f32
    const float* __restrict__ maskb,           // [8192][8]
    float* __restrict__ out)
{
    __shared__ unsigned short As[64][72];
    __shared__ unsigned short Bg[64][72];
    __shared__ unsigned short Bf[64][72];
    const int tid = threadIdx.x;
    const int wave = tid >> 6, lane = tid & 63;
    const int wr = wave >> 1, wc = wave & 1;
    const int lr = lane & 15, lo = lane >> 4;
    const int rowBase = blockIdx.y * 64, colBase = blockIdx.x * 64;

#pragma unroll
    for (int i = 0; i < 2; ++i) {
        int c = i*256 + tid;
        int r = c >> 3, kc = (c & 7) << 3;
        *(uint4*)&As[r][kc] = *(const uint4*)(o + (size_t)(rowBase + r) * 64 + kc);
        *(uint4*)&Bg[r][kc] = *(const uint4*)(gfc_t + (size_t)(colBase + r) * 64 + kc);
        *(uint4*)&Bf[r][kc] = *(const uint4*)(gfc_t + 8192 + (size_t)(colBase + r) * 64 + kc);
    }
    __syncthreads();

    const f32x4 zero = {0.f, 0.f, 0.f, 0.f};
    f32x4 ag[2][2], af[2][2];
    ag[0][0]=zero; ag[0][1]=zero; ag[1][0]=zero; ag[1][1]=zero;
    af[0][0]=zero; af[0][1]=zero; af[1][0]=zero; af[1][1]=zero;
#pragma unroll
    for (int ks = 0; ks < 64; ks += 32) {
        bf16x8 a0 = *(const bf16x8*)&As[wr*32 + lr][ks + lo*8];
        bf16x8 a1 = *(const bf16x8*)&As[wr*32 + 16 + lr][ks + lo*8];
        bf16x8 g0 = *(const bf16x8*)&Bg[wc*32 + lr][ks + lo*8];
        bf16x8 g1 = *(const bf16x8*)&Bg[wc*32 + 16 + lr][ks + lo*8];
        bf16x8 f0 = *(const bf16x8*)&Bf[wc*32 + lr][ks + lo*8];
        bf16x8 f1 = *(const bf16x8*)&Bf[wc*32 + 16 + lr][ks + lo*8];
        ag[0][0] = __builtin_amdgcn_mfma_f32_16x16x32_bf16(a0,g0,ag[0][0],0,0,0);
        ag[0][1] = __builtin_amdgcn_mfma_f32_16x16x32_bf16(a0,g1,ag[0][1],0,0,0);
        ag[1][0] = __builtin_amdgcn_mfma_f32_16x16x32_bf16(a1,g0,ag[1][0],0,0,0);
        ag[1][1] = __builtin_amdgcn_mfma_f32_16x16x32_bf16(a1,g1,ag[1][1],0,0,0);
        af[0][0] = __builtin_amdgcn_mfma_f32_16x16x32_bf16(a0,f0,af[0][0],0,0,0);
        af[0][1] = __builtin_amdgcn_mfma_f32_16x16x32_bf16(a0,f1,af[0][1],0,0,0);
        af[1][0] = __builtin_amdgcn_mfma_f32_16x16x32_bf16(a1,f0,af[1][0],0,0,0);
        af[1][1] = __builtin_amdgcn_mfma_f32_16x16x32_bf16(a1,f1,af[1][1],0,0,0);
    }
#pragma unroll
    for (int i = 0; i < 2; ++i)
#pragma unroll
    for (int j = 0; j < 2; ++j)
#pragma unroll
    for (int r = 0; r < 4; ++r) {
        int m   = rowBase + wr*32 + i*16 + lo*4 + r;   // = b*8+qb
        int col = colBase + wc*32 + j*16 + lr;
        float g = sigmoidf_(ag[i][j][r] + gate_b[col]);
        float f = tanhf(af[i][j][r] + fc_b[col]);
        float att = g * f;
        size_t oidx = (size_t)m * 128 + col;
        float msk = maskb[m];
        float hnv = bf2f(hxn[oidx]) + att;
        out[oidx] = msk * hnv + (1.f - msk) * hx[oidx];
        out[(size_t)NB * 1024 + oidx] = msk;
    }
}

// ---------------------------------------------------------------------------
extern "C" void kernel_launch(void* const* d_in, const int* in_sizes, int n_in,
                              void* d_out, int out_size, void* d_ws, size_t ws_size,
                              hipStream_t stream)
{
    (void)in_sizes; (void)n_in; (void)out_size; (void)ws_size;
    const float* inp    = (const float*)d_in[0];
    const float* hx     = (const float*)d_in[1];
    const float* Wq1    = (const float*)d_in[3];
    const float* Wk1    = (const float*)d_in[4];
    const float* Wv1    = (const float*)d_in[5];
    const float* Wq2    = (const float*)d_in[6];
    const float* Wk2    = (const float*)d_in[7];
    const float* Wv2    = (const float*)d_in[8];
    const float* fc_w   = (const float*)d_in[9];
    const float* fc_b   = (const float*)d_in[10];
    const float* gate_w = (const float*)d_in[11];
    const float* gate_b = (const float*)d_in[12];
    const float* gwi    = (const float*)d_in[13];
    const float* gwh    = (const float*)d_in[14];
    const float* gbi    = (const float*)d_in[15];
    const float* gbh    = (const float*)d_in[16];
    float* out = (float*)d_out;

    // ---- workspace arena (byte offsets; total ~124.2 MB) ----
    char* W = (char*)d_ws;
    float* cbuf  = (float*)(W + 0x0);
    float* maskb = (float*)(W + 0x40000);
    float* kk1f  = (float*)(W + 0x80000);            // [8192*64]   2 MB
    float* qbuff = (float*)(W + 0x280000);           // [8192*512] 16 MB
    unsigned short* inp_bf = (unsigned short*)(W + 0x1280000);  // 4 MB
    unsigned short* hx_bf  = (unsigned short*)(W + 0x1680000);  // 16 MB
    unsigned short* wi_t   = (unsigned short*)(W + 0x2680000);  // [8][384][512] 3 MB
    unsigned short* wh_t   = (unsigned short*)(W + 0x2980000);  // [8][384][128] .75 MB
    unsigned short* w2_t   = (unsigned short*)(W + 0x2A40000);  // [8][192][128] .375 MB
    unsigned short* gfc_t  = (unsigned short*)(W + 0x2AA0000);  // [2][128][64]  32 KB
    unsigned short* wc_t   = (unsigned short*)(W + 0x2AA8000);  // [8][384][256] 1.5 MB
    unsigned short* comb   = (unsigned short*)(W + 0x2C28000);  // [8][8192][512] 64 MB
    unsigned short* hxn    = (unsigned short*)(W + 0x6C28000);  // [8192][1024] 16 MB
    unsigned short* qkv    = comb;                               // reuse (comb dead after gru)
    unsigned short* o_bf   = (unsigned short*)(W + 0x2C28000 + 25165824);  // +24 MB

    const dim3 blk(256);

    // (1) score path: f32 GEMMs, f64 final dot + ranking
    gemm_nn<<<dim3(1, 128, 1), blk, 0, stream>>>(inp, 256, 0, Wk1 + 256*64, 0, 64, kk1f, 64, 0, 256);
    gemm_nn<<<dim3(1, 128, 8), blk, 0, stream>>>(hx, 1024, 128, Wq1, 128*64, 64, qbuff, 512, 64, 128);
    score_mask_k<<<dim3(32), blk, 0, stream>>>(qbuff, kk1f, cbuf, maskb);

    // (2) casts + weight prep
    cast_bf<<<dim3(10240), blk, 0, stream>>>(inp, hx, inp_bf, hx_bf);
    prep_w<<<dim3(8512), blk, 0, stream>>>(gwi, gwh, Wq2, Wk2, Wv2, gate_w, fc_w,
                                           wi_t, wh_t, w2_t, gfc_t);

    // (3) wcomb = Wv1[1] @ gwi -> wc_t [8][384][256]
    gemm_bf<1, 1><<<dim3(6, 4, 8), blk, 0, stream>>>(
        Wv1 + 256*512, 512, 0, wi_t, 384*512, 512, wc_t, 256, (long)384*256, 512);

    // (4) fused gx/gh GEMM -> comb  (bf16 A, N=128/block)
    gemm_gxh<<<dim3(3, 128, 8), blk, 0, stream>>>(inp_bf, wc_t, hx_bf, wh_t, cbuf, gbi, gbh, comb);

    // (5) GRU pointwise -> hxn (bf16)
    gru_all<<<dim3(32768), blk, 0, stream>>>(comb, hx, hxn);

    // (6) q2|k2|v2 = hxn_k @ W2cat -> qkv bf16 [8192][1536]
    gemm_bf<0, 0><<<dim3(3, 128, 8), blk, 0, stream>>>(
        hxn, 1024, 128, w2_t, 192*128, 128, qkv, 1536, 192L, 128);

    // (7) attention-2 -> o_bf
    attn2_bf<<<dim3(1024), blk, 0, stream>>>(qkv, o_bf);

    // (8) gate/fc MFMA + mask combine -> f32 outputs
    gatefc_final<<<dim3(2, 1024), blk, 0, stream>>>(o_bf, gfc_t, gate_b, fc_b,
                                                    hxn, hx, maskb, out);
}